// Round 7
// baseline (394.404 us; speedup 1.0000x reference)
//
#include <hip/hip_runtime.h>
#include <hip/hip_bf16.h>

typedef __bf16 bf16_t;
typedef __bf16 bf16x8 __attribute__((ext_vector_type(8)));
typedef float f32x4 __attribute__((ext_vector_type(4)));

static constexpr int Mm = 3, Bb = 8, Ss = 512, Dd = 768;
static constexpr float NORMF = 0.036084391824351615f; // 1/sqrt(768)

enum { EPI_PROJ = 0, EPI_E, EPI_CONF, EPI_BF16, EPI_F32 };

// async global->LDS, 16B per lane. LDS dest must be wave-uniform; HW adds lane*16.
__device__ __forceinline__ void gload16(const void* g, void* l) {
    __builtin_amdgcn_global_load_lds(
        (const __attribute__((address_space(1))) void*)g,
        (__attribute__((address_space(3))) void*)l, 16, 0, 0);
}

#define FENCE() do { asm volatile("" ::: "memory"); __builtin_amdgcn_sched_barrier(0); } while (0)
#define BARRIER() do { FENCE(); __builtin_amdgcn_s_barrier(); FENCE(); } while (0)

typedef bf16_t ldsrow_t[8192];

// ============================ 256x256 8-phase GEMM core =====================
// C[row,col] = epi( sum_k A[row,k] * Bt[col,k] ), NT form, bf16 in, f32 acc.
// 512 threads = 8 waves (2 row-groups x 4 col-groups); per-wave out 128x64.
// LDS (caller-owned 128 KiB): 8 half-slots of 16KB: slot(buf,part),
// part={0:B-k0,1:A-k0,2:B-k1,3:A-k1}.
// Each phase: ds-read frag subtile + stage 1 half-slot (2 gloads) + barrier +
// lgkmcnt(0) + 16 MFMA; counted vmcnt(6) only at phases 4/8 end.
// Half h: tile=h>>2 (mod NKT), buf=(h>>2)&1, part=h&3.
// Staging targets the slot freed at the previous phase-end barrier (all waves'
// ds_reads of that slot drained at their lgkmcnt(0) before that barrier);
// vmcnt(6) at ph4/ph8 end guarantees the tile consumed 4 phases later is
// resident. Bank swizzle (both sides, rule #21): 16B-chunk' = chunk ^ ((row>>1)&3).
template<int EPI, int K>
__device__ __forceinline__ void gemm8_core(
    ldsrow_t* __restrict__ lds,
    const bf16_t* __restrict__ Ap, const bf16_t* __restrict__ Bp,
    int lda, int ldb, void* __restrict__ Cp, int ldc,
    const float* __restrict__ bias, float scale,
    int rowBase, int colBase)
{
    constexpr int NKT = K / 64;                 // 12 (K=768) or 8 (K=512)

    const int tid = threadIdx.x, lane = tid & 63, wv = tid >> 6;
    const int wr = wv >> 2, wc = wv & 3;
    const int lg = lane >> 4, l16 = lane & 15;
    const int swz8 = (lg ^ ((l16 >> 1) & 3)) * 8;   // ds_read chunk swizzle (elements)

    f32x4 acc[8][4] = {};
    bf16x8 af[4], bfr[4];

#define STAGE(hh) do {                                                        \
    const int t_  = ((hh) >> 2) % NKT;                                        \
    const int p_  = (hh) & 3;                                                 \
    const int sl_ = (((hh) >> 2) & 1) * 4 + p_;                               \
    const bf16_t* s_ = (p_ & 1) ? Ap : Bp;                                    \
    const int ld_ = (p_ & 1) ? lda : ldb;                                     \
    const int rb_ = (p_ & 1) ? rowBase : colBase;                             \
    const int kb_ = t_ * 64 + (p_ >> 1) * 32;                                 \
    _Pragma("unroll")                                                         \
    for (int q_ = 0; q_ < 2; ++q_) {                                          \
        const int row_ = (wv * 2 + q_) * 16 + (lane >> 2);                    \
        const int ck_  = (lane & 3) ^ ((row_ >> 1) & 3);                      \
        gload16(s_ + (size_t)(rb_ + row_) * ld_ + kb_ + ck_ * 8,              \
                (char*)&lds[sl_][0] + (wv * 2 + q_) * 1024);                  \
    }                                                                         \
} while (0)

#define RD_A(sl_, rh_) do {                                                   \
    _Pragma("unroll")                                                         \
    for (int rf_ = 0; rf_ < 4; ++rf_)                                         \
        af[rf_] = *(const bf16x8*)&lds[sl_][(wr*128 + (rh_)*64 + rf_*16 + l16)*32 + swz8]; \
} while (0)

#define RD_B(sl_) do {                                                        \
    _Pragma("unroll")                                                         \
    for (int cf_ = 0; cf_ < 4; ++cf_)                                         \
        bfr[cf_] = *(const bf16x8*)&lds[sl_][(wc*64 + cf_*16 + l16)*32 + swz8]; \
} while (0)

#define PHASE(bb_, ks_, rh_, LAST_) do {                                      \
    if (rh_ == 0) RD_B((bb_)*4 + (ks_)*2);                                    \
    RD_A((bb_)*4 + (ks_)*2 + 1, rh_);                                         \
    STAGE(h); ++h;                                                            \
    BARRIER();                                                                \
    asm volatile("s_waitcnt lgkmcnt(0)" ::: "memory");                        \
    __builtin_amdgcn_sched_barrier(0);                                        \
    __builtin_amdgcn_s_setprio(1);                                            \
    _Pragma("unroll")                                                         \
    for (int rf_ = 0; rf_ < 4; ++rf_) {                                       \
        _Pragma("unroll")                                                     \
        for (int cf_ = 0; cf_ < 4; ++cf_)                                     \
            acc[(rh_)*4 + rf_][cf_] = __builtin_amdgcn_mfma_f32_16x16x32_bf16( \
                af[rf_], bfr[cf_], acc[(rh_)*4 + rf_][cf_], 0, 0, 0);         \
    }                                                                         \
    __builtin_amdgcn_s_setprio(0);                                            \
    if (LAST_) { asm volatile("s_waitcnt vmcnt(6)" ::: "memory"); }           \
    BARRIER();                                                                \
} while (0)

    int h = 0;
    #pragma unroll
    for (int p = 0; p < 7; ++p) { STAGE(h); ++h; }     // tile0 (4) + tile1 (3 of 4)
    asm volatile("s_waitcnt vmcnt(6)" ::: "memory");   // tile0 fully resident
    BARRIER();

    for (int it = 0; it < NKT / 2; ++it) {
        PHASE(0, 0, 0, false); PHASE(0, 0, 1, false);
        PHASE(0, 1, 0, false); PHASE(0, 1, 1, true);
        PHASE(1, 0, 0, false); PHASE(1, 0, 1, false);
        PHASE(1, 1, 0, false); PHASE(1, 1, 1, true);
    }

    // Drain the 6 tail prefetch DMAs: a stale LDS-DMA landing after s_endpgm
    // could corrupt a newly-scheduled block's LDS (R2-class replay race).
    asm volatile("s_waitcnt vmcnt(0)" ::: "memory");
    __builtin_amdgcn_sched_barrier(0);

#undef PHASE
#undef RD_A
#undef RD_B
#undef STAGE

    // epilogue
    #pragma unroll
    for (int cf = 0; cf < 4; ++cf) {
        const int gc = colBase + wc * 64 + cf * 16 + l16;
        const float bv = (EPI == EPI_PROJ || EPI == EPI_CONF) ? bias[gc] : 0.f;
        #pragma unroll
        for (int rg = 0; rg < 8; ++rg) {
            #pragma unroll
            for (int r = 0; r < 4; ++r) {
                const int gr = rowBase + wr * 128 + rg * 16 + lg * 4 + r;
                float v = acc[rg][cf][r];
                if (EPI == EPI_PROJ) {
                    v = fmaxf(v + bv, 0.f);
                    ((bf16_t*)Cp)[(size_t)gr * ldc + gc] = (bf16_t)v;
                } else if (EPI == EPI_E) {
                    v = fmaxf(v * scale, 0.f);
                    ((bf16_t*)Cp)[(size_t)gr * ldc + gc] = (bf16_t)v;
                } else if (EPI == EPI_CONF) {
                    v = 1.f / (1.f + __expf(-(v + bv)));
                    ((bf16_t*)Cp)[(size_t)gr * ldc + gc] = (bf16_t)v;
                } else if (EPI == EPI_BF16) {
                    ((bf16_t*)Cp)[(size_t)gr * ldc + gc] = (bf16_t)v;
                } else {
                    ((float*)Cp)[(size_t)gr * ldc + gc] = v;
                }
            }
        }
    }
}

// ---- GEMM kernels (flat grid, XCD-chunk swizzle; all grids %8==0) ----------

__device__ __forceinline__ int xcd_swz(int n) {
    return (blockIdx.x & 7) * (n >> 3) + (blockIdx.x >> 3);
}

__global__ __launch_bounds__(512) void k_proj8(const bf16_t* __restrict__ modB,
                                               const bf16_t* __restrict__ WpB,
                                               const float* __restrict__ bp,
                                               bf16_t* __restrict__ proj) {
    __shared__ bf16_t lds[8][8192];            // 128 KiB
    const int wid = xcd_swz(144);              // 3 m x (16 x 3)
    const int m = wid / 48, rem = wid % 48;
    const int by = rem / 3, bx = rem % 3;
    gemm8_core<EPI_PROJ, 768>(lds,
        modB + (size_t)m * Bb * Ss * Dd, WpB + (size_t)m * Dd * Dd, Dd, Dd,
        proj + (size_t)m * Bb * Ss * Dd, Dd, bp + m * Dd, 1.f,
        by * 256, bx * 256);
}

__global__ __launch_bounds__(512) void k_scoresconf(const bf16_t* __restrict__ proj,
                                                    const bf16_t* __restrict__ wcbf,
                                                    const float* __restrict__ bc,
                                                    bf16_t* __restrict__ E,
                                                    bf16_t* __restrict__ conf) {
    __shared__ bf16_t lds[8][8192];            // 128 KiB, shared by both branches
    const int wid = xcd_swz(384);
    const size_t SS = (size_t)Ss * Ss;
    if (wid < 288) {                           // scores: 72 z x (2x2)
        const int z = wid >> 2, q = wid & 3;
        const int i = z / 24, j = (z / 8) % 3, b = z % 8;
        gemm8_core<EPI_E, 768>(lds,
            proj + (size_t)(i * Bb + b) * Ss * Dd,
            proj + (size_t)(j * Bb + b) * Ss * Dd, Dd, Dd,
            E + z * SS, Ss, nullptr, NORMF, (q >> 1) * 256, (q & 1) * 256);
    } else {                                   // conf: 24 z x (2x2)
        const int w2 = wid - 288;
        const int z = w2 >> 2, q = w2 & 3;
        gemm8_core<EPI_CONF, 768>(lds,
            proj + (size_t)z * Ss * Dd, wcbf, Dd, Dd,
            conf + z * SS, Ss, bc, 1.f, (q >> 1) * 256, (q & 1) * 256);
    }
}

__global__ __launch_bounds__(512) void k_s28(const bf16_t* __restrict__ P,
                                             const bf16_t* __restrict__ Pt,
                                             bf16_t* __restrict__ S2) {
    __shared__ bf16_t lds[8][8192];
    const int wid = xcd_swz(288);
    const int z = wid >> 2, q = wid & 3;
    const size_t SS = (size_t)Ss * Ss;
    gemm8_core<EPI_BF16, 512>(lds,
        P + z * SS, Pt + z * SS, Ss, Ss,
        S2 + z * SS, Ss, nullptr, 1.f, (q >> 1) * 256, (q & 1) * 256);
}

__global__ __launch_bounds__(512) void k_out8(const bf16_t* __restrict__ S2,
                                              const bf16_t* __restrict__ projT,
                                              float* __restrict__ outp) {
    __shared__ bf16_t lds[8][8192];
    const int wid = xcd_swz(432);              // 72 z x (2 x 3)
    const int z = wid / 6, q = wid % 6;
    const int j = (z / 8) % 3, b = z % 8;
    gemm8_core<EPI_F32, 512>(lds,
        S2 + (size_t)z * Ss * Ss,
        projT + (size_t)(j * Bb + b) * Dd * Ss, Ss, Ss,
        outp + (size_t)z * Ss * Dd, Dd, nullptr, 1.f,
        (q / 3) * 256, (q % 3) * 256);
}

// ---- non-GEMM kernels (validated in R3, unchanged) -------------------------

__global__ __launch_bounds__(256) void k_transpose(const bf16_t* __restrict__ in,
                                                   bf16_t* __restrict__ out,
                                                   int R, int C) {
    __shared__ bf16_t t[64][80];
    const size_t z = blockIdx.z;
    const bf16_t* ip = in + z * (size_t)R * C;
    bf16_t* op = out + z * (size_t)R * C;
    const int r0 = blockIdx.y * 64, c0 = blockIdx.x * 64;
    const int tid = threadIdx.x;
    #pragma unroll
    for (int it = 0; it < 2; ++it) {
        const int c = tid + it * 256;
        const int r = c >> 3, cc = (c & 7) * 8;
        *(bf16x8*)&t[r][cc] = *(const bf16x8*)(ip + (size_t)(r0 + r) * C + c0 + cc);
    }
    __syncthreads();
    #pragma unroll
    for (int it = 0; it < 2; ++it) {
        const int c = tid + it * 256;
        const int oc = c >> 3, rr = (c & 7) * 8;
        bf16x8 v;
        #pragma unroll
        for (int k = 0; k < 8; ++k) v[k] = t[rr + k][oc];
        *(bf16x8*)(op + (size_t)(c0 + oc) * R + r0 + rr) = v;
    }
}

__device__ __forceinline__ int lidx(int r, int c) {
    int cb = (c >> 3) ^ (r & 7) ^ ((r >> 3) & 7);
    return r * 512 + cb * 8 + (c & 7);
}

__global__ __launch_bounds__(256) void k_softmaxT(const bf16_t* __restrict__ E,
                                                  bf16_t* __restrict__ P,
                                                  bf16_t* __restrict__ Pt) {
    __shared__ bf16_t L[64 * 512];
    const int z = blockIdx.y, strip = blockIdx.x;
    const size_t SS = (size_t)Ss * Ss;
    const bf16_t* ep = E + (size_t)z * SS + (size_t)strip * 64 * Ss;
    const int tid = threadIdx.x, lane = tid & 63, wv = tid >> 6;

    #pragma unroll 4
    for (int rr = 0; rr < 16; ++rr) {
        const int r = wv * 16 + rr;
        const bf16x8 v8 = *(const bf16x8*)(ep + (size_t)r * Ss + lane * 8);
        float v[8];
        float mx = -1e30f;
        #pragma unroll
        for (int q = 0; q < 8; ++q) { v[q] = (float)v8[q]; mx = fmaxf(mx, v[q]); }
        #pragma unroll
        for (int off = 1; off < 64; off <<= 1) mx = fmaxf(mx, __shfl_xor(mx, off, 64));
        float e[8], s = 0.f;
        #pragma unroll
        for (int q = 0; q < 8; ++q) { e[q] = __expf(v[q] - mx); s += e[q]; }
        #pragma unroll
        for (int off = 1; off < 64; off <<= 1) s += __shfl_xor(s, off, 64);
        const float inv = 1.f / s;
        bf16x8 o;
        #pragma unroll
        for (int q = 0; q < 8; ++q) o[q] = (bf16_t)(e[q] * inv);
        *(bf16x8*)&L[lidx(r, lane * 8)] = o;
    }
    __syncthreads();

    bf16_t* pp = P + (size_t)z * SS + (size_t)strip * 64 * Ss;
    #pragma unroll
    for (int k = 0; k < 16; ++k) {
        const int cc = tid + k * 256;
        const int r = cc >> 6, c8 = (cc & 63) * 8;
        *(bf16x8*)(pp + (size_t)r * Ss + c8) = *(const bf16x8*)&L[lidx(r, c8)];
    }
    bf16_t* pt = Pt + (size_t)z * SS + strip * 64;
    #pragma unroll
    for (int k = 0; k < 16; ++k) {
        const int cc = tid + k * 256;
        const int t = cc >> 3, s8 = (cc & 7) * 8;
        bf16x8 o;
        #pragma unroll
        for (int q = 0; q < 8; ++q) o[q] = L[lidx(s8 + q, t)];
        *(bf16x8*)(pt + (size_t)t * Ss + s8) = o;
    }
}

// f32 -> bf16 pre-convert (modality, Wp, Wc) + zero loss slot
__global__ __launch_bounds__(256) void k_prep(const float* __restrict__ mod,
                                              const float* __restrict__ Wp,
                                              const float* __restrict__ Wc,
                                              bf16_t* __restrict__ modB,
                                              bf16_t* __restrict__ WpB,
                                              bf16_t* __restrict__ wcbf,
                                              float* __restrict__ out0) {
    const int c = blockIdx.x * 256 + threadIdx.x;   // 1,449,984 chunks of 8
    if (c == 0) out0[0] = 0.f;
    const float* src; bf16_t* dst; size_t off;
    if (c < 1179648)       { src = mod; dst = modB; off = (size_t)c * 8; }
    else if (c < 1400832)  { src = Wp;  dst = WpB;  off = (size_t)(c - 1179648) * 8; }
    else                   { src = Wc;  dst = wcbf; off = (size_t)(c - 1400832) * 8; }
    const f32x4 a = *(const f32x4*)(src + off);
    const f32x4 b = *(const f32x4*)(src + off + 4);
    bf16x8 v;
    #pragma unroll
    for (int q = 0; q < 4; ++q) { v[q] = (bf16_t)a[q]; v[q + 4] = (bf16_t)b[q]; }
    *(bf16x8*)(dst + off) = v;
}

__global__ __launch_bounds__(256) void k_loss(const bf16_t* __restrict__ P,
                                              const bf16_t* __restrict__ conf,
                                              float* __restrict__ out0) {
    const size_t NE = (size_t)Mm * Bb * Ss * Ss;
    const size_t NCH = NE / 8;
    float local = 0.f;
    for (size_t c = blockIdx.x * (size_t)256 + threadIdx.x; c < NCH;
         c += gridDim.x * (size_t)256) {
        const size_t base = c * 8;
        const bf16x8 s0 = *(const bf16x8*)(P + base);
        const bf16x8 s1 = *(const bf16x8*)(P + base + NE);
        const bf16x8 s2 = *(const bf16x8*)(P + base + 2 * NE);
        const bf16x8 cf = *(const bf16x8*)(conf + base);
        #pragma unroll
        for (int k = 0; k < 8; ++k) {
            const float d = (float)s0[k] + (float)s1[k] + (float)s2[k] - (float)cf[k];
            local += d * d;
        }
    }
    #pragma unroll
    for (int off = 1; off < 64; off <<= 1) local += __shfl_xor(local, off, 64);
    __shared__ float wsum[4];
    if ((threadIdx.x & 63) == 0) wsum[threadIdx.x >> 6] = local;
    __syncthreads();
    if (threadIdx.x == 0) {
        const float s = wsum[0] + wsum[1] + wsum[2] + wsum[3];
        atomicAdd(out0, s * (1.0f / (float)NE));
    }
}

// ---- launch ----------------------------------------------------------------

extern "C" void kernel_launch(void* const* d_in, const int* in_sizes, int n_in,
                              void* d_out, int out_size, void* d_ws, size_t ws_size,
                              hipStream_t stream) {
    const float* modality = (const float*)d_in[0];
    const float* Wp = (const float*)d_in[1];
    const float* bp = (const float*)d_in[2];
    const float* Wc = (const float*)d_in[3];
    const float* bc = (const float*)d_in[4];
    float* out = (float*)d_out;          // [0]=loss, [1..]=out flat [i,j,b,s,d]

    char* ws = (char*)d_ws;
    bf16_t* modB  = (bf16_t*)(ws + 0);                       // 18,874,368
    bf16_t* WpB   = (bf16_t*)(ws + 18874368);                //  3,538,944
    bf16_t* wcbf  = (bf16_t*)(ws + 22413312);                //    786,432
    bf16_t* proj  = (bf16_t*)(ws + 23199744);                // 18,874,368
    bf16_t* projT = (bf16_t*)(ws + 42074112);                // 18,874,368
    bf16_t* P     = (bf16_t*)(ws + 60948480);                // 37,748,736
    bf16_t* Pt    = (bf16_t*)(ws + 98697216);                // 37,748,736
    bf16_t* E     = (bf16_t*)(ws + 136445952);               // 37,748,736 (dead after softmaxT)
    bf16_t* S2    = (bf16_t*)(ws + 136445952);               // aliases E
    bf16_t* conf  = (bf16_t*)(ws + 174194688);               // 12,582,912 (end 186,777,600)

    k_prep<<<dim3(5664), 256, 0, stream>>>(modality, Wp, Wc, modB, WpB, wcbf, out);
    k_proj8<<<dim3(144), 512, 0, stream>>>(modB, WpB, bp, proj);
    k_transpose<<<dim3(Dd / 64, Ss / 64, Mm * Bb), 256, 0, stream>>>(proj, projT, Ss, Dd);
    k_scoresconf<<<dim3(384), 512, 0, stream>>>(proj, wcbf, bc, E, conf);
    k_softmaxT<<<dim3(Ss / 64, Mm * Mm * Bb), 256, 0, stream>>>(E, P, Pt);
    k_s28<<<dim3(288), 512, 0, stream>>>(P, Pt, S2);
    k_out8<<<dim3(432), 512, 0, stream>>>(S2, projT, out + 1);
    k_loss<<<dim3(1024), 256, 0, stream>>>(P, conf, out);
}